// Round 1
// baseline (1015.681 us; speedup 1.0000x reference)
//
#include <hip/hip_runtime.h>

#define CDIM 128
#define NSRC 100000
#define NDST 40000
#define NEDGE 500000

typedef short bf8_t __attribute__((ext_vector_type(8)));
typedef float f32x4 __attribute__((ext_vector_type(4)));

static __device__ __forceinline__ unsigned short f2bf(float f) {
    unsigned int u = __float_as_uint(f);
    u = (u + 0x7fffu + ((u >> 16) & 1u)) >> 16;
    return (unsigned short)u;
}

// Transpose + bf16-convert all weight matrices into workspace.
// w1t [128][384], w2t [128][128], nw1t [128][256], nw1st [128][128] (top+bot summed), nw2t [128][128]
__global__ void prep_weights(const float* __restrict__ ew1, const float* __restrict__ ew2,
                             const float* __restrict__ nw1, const float* __restrict__ nw2,
                             unsigned short* __restrict__ w1t, unsigned short* __restrict__ w2t,
                             unsigned short* __restrict__ nw1t, unsigned short* __restrict__ nw1st,
                             unsigned short* __restrict__ nw2t) {
    int i = blockIdx.x * blockDim.x + threadIdx.x;
    if (i < 128 * 384) { int n = i / 384, k = i % 384; w1t[i] = f2bf(ew1[k * 128 + n]); return; }
    i -= 128 * 384;
    if (i < 128 * 128) { int n = i / 128, k = i % 128; w2t[i] = f2bf(ew2[k * 128 + n]); return; }
    i -= 128 * 128;
    if (i < 128 * 256) { int n = i / 256, k = i % 256; nw1t[i] = f2bf(nw1[k * 128 + n]); return; }
    i -= 128 * 256;
    if (i < 128 * 128) { int n = i / 128, k = i % 128; nw1st[i] = f2bf(nw1[k * 128 + n] + nw1[(k + 128) * 128 + n]); return; }
    i -= 128 * 128;
    if (i < 128 * 128) { int n = i / 128, k = i % 128; nw2t[i] = f2bf(nw2[k * 128 + n]); return; }
}

// Fused MLP: y = LN(silu(A@W1 + b1)@W2 + b2)*gamma + beta  [+ residual] [+ atomic segment-sum]
// A rows are concat of NCHUNK 128-wide segments, optionally gathered via idx.
// Block tile: 128 rows x 128 cols, 4 waves in 2x2 (each wave 64x64 via 4x4 mfma_16x16x32 tiles).
template <int NCHUNK>
__global__ __launch_bounds__(256, 2) void mlp_fused(
    const float* __restrict__ seg0, const int* __restrict__ idx0,
    const float* __restrict__ seg1, const int* __restrict__ idx1,
    const float* __restrict__ seg2,
    const unsigned short* __restrict__ W1t, const float* __restrict__ b1,
    const unsigned short* __restrict__ W2t, const float* __restrict__ b2,
    const float* __restrict__ gamma, const float* __restrict__ beta,
    float* __restrict__ out, const float* __restrict__ residual,
    float* __restrict__ agg, const int* __restrict__ aggidx, int nrows) {

    __shared__ unsigned short Abuf[128 * 136];   // A chunk / h buffer (aliased), stride 136 pads banks
    __shared__ unsigned short Wbuf[128 * 136];   // W chunk (transposed: [n][k])
    __shared__ float rstats[128][2][2];          // per-row partial {sum, sumsq} per col-half

    const int tid = threadIdx.x;
    const int lane = tid & 63;
    const int wave = tid >> 6;
    const int t = lane & 15;   // A-row / B-col index within 16-tile
    const int q = lane >> 4;   // quad
    const int rw = wave >> 1;  // row half (0/1)
    const int cw = wave & 1;   // col half (0/1)
    const int row0 = blockIdx.x * 128;
    const int K1 = NCHUNK * 128;

    const f32x4 zero4 = {0.f, 0.f, 0.f, 0.f};
    f32x4 acc[4][4];
#pragma unroll
    for (int a = 0; a < 4; a++)
#pragma unroll
        for (int b = 0; b < 4; b++) acc[a][b] = zero4;

#pragma unroll
    for (int c = 0; c < NCHUNK; c++) {
        // ---- stage A chunk: 128 rows x 128 cols fp32 -> bf16 ----
        {
            const float* seg = (c == 0) ? seg0 : ((c == 1) ? seg1 : seg2);
            const int* idx = (c == 0) ? idx0 : ((c == 1) ? idx1 : (const int*)nullptr);
            int r = tid >> 1;
            int hh = tid & 1;
            int grow = row0 + r;
            const float4* src = nullptr;
            if (grow < nrows) {
                long g = idx ? (long)idx[grow] : (long)grow;
                src = (const float4*)(seg + g * CDIM) + hh * 16;
            }
            unsigned short* dst = &Abuf[r * 136 + hh * 64];
#pragma unroll
            for (int i = 0; i < 16; i++) {
                float4 v = src ? src[i] : make_float4(0.f, 0.f, 0.f, 0.f);
                ushort4 p;
                p.x = f2bf(v.x); p.y = f2bf(v.y); p.z = f2bf(v.z); p.w = f2bf(v.w);
                *(ushort4*)(dst + i * 4) = p;
            }
        }
        // ---- stage W1 chunk: Wbuf[n][kk] = W1t[n][c*128+kk] ----
        {
            int n = tid >> 1;
            int hh = tid & 1;
            const unsigned short* src = W1t + n * K1 + c * 128 + hh * 64;
            unsigned short* dst = &Wbuf[n * 136 + hh * 64];
#pragma unroll
            for (int i = 0; i < 8; i++)
                *(int4*)(dst + i * 8) = *(const int4*)(src + i * 8);
        }
        __syncthreads();
        // ---- GEMM1 on chunk: 4 K-steps of 32 ----
#pragma unroll
        for (int ks = 0; ks < 4; ks++) {
            bf8_t av[4], bv[4];
#pragma unroll
            for (int mt = 0; mt < 4; mt++)
                av[mt] = *(const bf8_t*)&Abuf[(rw * 64 + mt * 16 + t) * 136 + ks * 32 + q * 8];
#pragma unroll
            for (int nt = 0; nt < 4; nt++)
                bv[nt] = *(const bf8_t*)&Wbuf[(cw * 64 + nt * 16 + t) * 136 + ks * 32 + q * 8];
#pragma unroll
            for (int mt = 0; mt < 4; mt++)
#pragma unroll
                for (int nt = 0; nt < 4; nt++)
                    acc[mt][nt] = __builtin_amdgcn_mfma_f32_16x16x32_bf16(av[mt], bv[nt], acc[mt][nt], 0, 0, 0);
        }
        __syncthreads();
    }

    // ---- h = silu(acc + b1) -> bf16 into hbuf (alias Abuf; all GEMM1 reads done) ----
    unsigned short* hbuf = Abuf;
#pragma unroll
    for (int nt = 0; nt < 4; nt++) {
        int col = cw * 64 + nt * 16 + t;
        float bb = b1[col];
#pragma unroll
        for (int mt = 0; mt < 4; mt++)
#pragma unroll
            for (int r = 0; r < 4; r++) {
                float v = acc[mt][nt][r] + bb;
                v = v / (1.f + __expf(-v));
                hbuf[(rw * 64 + mt * 16 + q * 4 + r) * 136 + col] = f2bf(v);
            }
    }
    // ---- stage W2 ----
    {
        int n = tid >> 1;
        int hh = tid & 1;
        const unsigned short* src = W2t + n * 128 + hh * 64;
        unsigned short* dst = &Wbuf[n * 136 + hh * 64];
#pragma unroll
        for (int i = 0; i < 8; i++)
            *(int4*)(dst + i * 8) = *(const int4*)(src + i * 8);
    }
    __syncthreads();

    // ---- GEMM2: y = h @ W2 ----
    f32x4 acc2[4][4];
#pragma unroll
    for (int a = 0; a < 4; a++)
#pragma unroll
        for (int b = 0; b < 4; b++) acc2[a][b] = zero4;
#pragma unroll
    for (int ks = 0; ks < 4; ks++) {
        bf8_t av[4], bv[4];
#pragma unroll
        for (int mt = 0; mt < 4; mt++)
            av[mt] = *(const bf8_t*)&hbuf[(rw * 64 + mt * 16 + t) * 136 + ks * 32 + q * 8];
#pragma unroll
        for (int nt = 0; nt < 4; nt++)
            bv[nt] = *(const bf8_t*)&Wbuf[(cw * 64 + nt * 16 + t) * 136 + ks * 32 + q * 8];
#pragma unroll
        for (int mt = 0; mt < 4; mt++)
#pragma unroll
            for (int nt = 0; nt < 4; nt++)
                acc2[mt][nt] = __builtin_amdgcn_mfma_f32_16x16x32_bf16(av[mt], bv[nt], acc2[mt][nt], 0, 0, 0);
    }

    // ---- epilogue: +b2, layernorm stats (shfl within 16 lanes + cross-wave LDS) ----
#pragma unroll
    for (int nt = 0; nt < 4; nt++) {
        float bb = b2[cw * 64 + nt * 16 + t];
#pragma unroll
        for (int mt = 0; mt < 4; mt++)
#pragma unroll
            for (int r = 0; r < 4; r++) acc2[mt][nt][r] += bb;
    }
#pragma unroll
    for (int mt = 0; mt < 4; mt++)
#pragma unroll
        for (int r = 0; r < 4; r++) {
            float s = 0.f, s2 = 0.f;
#pragma unroll
            for (int nt = 0; nt < 4; nt++) {
                float v = acc2[mt][nt][r];
                s += v; s2 += v * v;
            }
#pragma unroll
            for (int m = 1; m < 16; m <<= 1) {
                s += __shfl_xor(s, m);
                s2 += __shfl_xor(s2, m);
            }
            if (t == 0) {
                int rr = rw * 64 + mt * 16 + q * 4 + r;
                rstats[rr][cw][0] = s;
                rstats[rr][cw][1] = s2;
            }
        }
    __syncthreads();

    float gam[4], bet[4];
#pragma unroll
    for (int nt = 0; nt < 4; nt++) {
        int col = cw * 64 + nt * 16 + t;
        gam[nt] = gamma[col];
        bet[nt] = beta[col];
    }
#pragma unroll
    for (int mt = 0; mt < 4; mt++)
#pragma unroll
        for (int r = 0; r < 4; r++) {
            int rr = rw * 64 + mt * 16 + q * 4 + r;
            float s = rstats[rr][0][0] + rstats[rr][1][0];
            float s2 = rstats[rr][0][1] + rstats[rr][1][1];
            float mu = s * (1.f / 128.f);
            float var = s2 * (1.f / 128.f) - mu * mu;
            float rs = rsqrtf(var + 1e-5f);
            int grow = row0 + rr;
            if (grow < nrows) {
                int gi = agg ? aggidx[grow] : 0;
#pragma unroll
                for (int nt = 0; nt < 4; nt++) {
                    int col = cw * 64 + nt * 16 + t;
                    float o = (acc2[mt][nt][r] - mu) * rs * gam[nt] + bet[nt];
                    if (residual) o += residual[(long)grow * CDIM + col];
                    out[(long)grow * CDIM + col] = o;
                    if (agg) unsafeAtomicAdd(&agg[(long)gi * CDIM + col], o);
                }
            }
        }
}

extern "C" void kernel_launch(void* const* d_in, const int* in_sizes, int n_in,
                              void* d_out, int out_size, void* d_ws, size_t ws_size,
                              hipStream_t stream) {
    const float* x_src = (const float*)d_in[0];
    const float* x_dst = (const float*)d_in[1];
    const float* edge_attr = (const float*)d_in[2];
    const int* edge_index = (const int*)d_in[3];
    const float* ew1 = (const float*)d_in[4];
    const float* eb1 = (const float*)d_in[5];
    const float* ew2 = (const float*)d_in[6];
    const float* eb2 = (const float*)d_in[7];
    const float* eg = (const float*)d_in[8];
    const float* ebn = (const float*)d_in[9];
    const float* nw1 = (const float*)d_in[10];
    const float* nb1 = (const float*)d_in[11];
    const float* nw2 = (const float*)d_in[12];
    const float* nb2 = (const float*)d_in[13];
    const float* ng = (const float*)d_in[14];
    const float* nbn = (const float*)d_in[15];

    const int* src_idx = edge_index;
    const int* dst_idx = edge_index + NEDGE;

    float* out_src = (float*)d_out;                     // [NSRC][C]
    float* out_dst = out_src + (size_t)NSRC * CDIM;     // [NDST][C]
    float* out_edge = out_dst + (size_t)NDST * CDIM;    // [NEDGE][C]

    char* ws = (char*)d_ws;
    float* agg = (float*)ws;  // [NDST][C] fp32 accumulator
    size_t off = (size_t)NDST * CDIM * sizeof(float);
    unsigned short* w1t = (unsigned short*)(ws + off);  off += (size_t)128 * 384 * 2;
    unsigned short* w2t = (unsigned short*)(ws + off);  off += (size_t)128 * 128 * 2;
    unsigned short* nw1t = (unsigned short*)(ws + off); off += (size_t)128 * 256 * 2;
    unsigned short* nw1st = (unsigned short*)(ws + off); off += (size_t)128 * 128 * 2;
    unsigned short* nw2t = (unsigned short*)(ws + off); off += (size_t)128 * 128 * 2;

    hipMemsetAsync(agg, 0, (size_t)NDST * CDIM * sizeof(float), stream);
    prep_weights<<<(131072 + 255) / 256, 256, 0, stream>>>(ew1, ew2, nw1, nw2, w1t, w2t, nw1t, nw1st, nw2t);

    // Edge MLP: rows = edges, A = [x_dst[dst] | x_src[src] | edge_attr]; writes edges_new + segment-sum
    mlp_fused<3><<<(NEDGE + 127) / 128, 256, 0, stream>>>(
        x_dst, dst_idx, x_src, src_idx, edge_attr,
        w1t, eb1, w2t, eb2, eg, ebn,
        out_edge, nullptr, agg, dst_idx, NEDGE);

    // Dst-node MLP: A = [x_dst | agg], + x_dst residual
    mlp_fused<2><<<(NDST + 127) / 128, 256, 0, stream>>>(
        x_dst, nullptr, agg, nullptr, nullptr,
        nw1t, nb1, nw2t, nb2, ng, nbn,
        out_dst, x_dst, nullptr, nullptr, NDST);

    // Src-node MLP: A = [x_src] with pre-summed W1 (concat(x,x)@W1 == x@(W1_top+W1_bot)), + x_src residual
    mlp_fused<1><<<(NSRC + 127) / 128, 256, 0, stream>>>(
        x_src, nullptr, nullptr, nullptr, nullptr,
        nw1st, nb1, nw2t, nb2, ng, nbn,
        out_src, x_src, nullptr, nullptr, NSRC);
}